// Round 4
// baseline (1808.162 us; speedup 1.0000x reference)
//
#include <hip/hip_runtime.h>
#include <math.h>

#define BB 32
#define NN 5000
#define EE 500
#define AT 50
#define TTT 4
#define ITT 24
#define FT 384
#define FI 383
#define KH 100
#define BN (BB*NN)

__device__ __forceinline__ float leaky(float x){ return x > 0.f ? x : 0.1f*x; }
__device__ __forceinline__ float sigm(float x){ return 1.f/(1.f+__expf(-x)); }

// workspace offsets (floats). ~32.4 MB total (ws proven >= 68 MB in round 1).
enum : size_t {
  O_WTT = 0,         // 19968  W_text^T padded [f][52]
  O_WIT = 19968,     // 19968  W_img^T padded [f][52] (row 383 zero)
  O_WIP = 39936,     // 10400  W_iproj*g padded [t*50+d][52]
  O_WTP = 50336,     // 62400  W_tproj*g padded [i*50+d][52]
  O_W1T = 112736,    // 50000  W1[:, :E]^T [e][100]
  O_W3T = 162736,    // 50000  W3^T [k][500]
  O_SIP = 212736,    // 208    sum_d Wg_iproj [t][52]
  O_STP = 212944,    // 1248   sum_d Wg_tproj [i][52]
  O_CBI = 214192,    // 52     2*sum(lnb*W_iproj)+b_iproj, pad 0
  O_CBT = 214244,    // 52
  O_RGI = 214296,    // 3072   sigmoid(rel@Wrel1^T+b) [b][96]
  O_RGT = 217368,    // 3072
  O_RB  = 220440,    // 3200   rel@W1[:,E:]^T [b][100]
  O_A   = 223640,    // 500000 ent@W1[:,:E]^T [n][100]
  O_PT  = 723640,    // 16000  pos_t [b][500]
  O_PTN = 739640,    // 32
  O_PIM = 739672,    // 1664   pos_img [b][52]
  O_PIMN= 741336,    // 32
  O_PTX = 741368,    // 1664
  O_PTXN= 743032,    // 32
  O_MR  = 743064,    // 96
  O_SR  = 743160,    // 96
  O_EMB = 743256,    // 7280000 emb [n][28][52]: rows 0..3 text, 4..27 img
  O_PTT = 8023256,   // 16384  pos_t transposed [e][32] (rows 500..511 unwritten)
  O_W3P = 8039640,   // 51200  W3^T padded [k][512] (cols 500..511 zero)
};

// ---------------- weight preprocessing ----------------
__global__ void k_prep(const float* Wt, const float* Wi, const float* Wip, const float* Wtp,
                       const float* W1, const float* W3, const float* g, const float* lb,
                       const float* bip, const float* btp, float* ws){
  int id = blockIdx.x*256 + threadIdx.x;
  if (id < 19968){ int f=id/52, d=id%52; ws[O_WTT+id] = (d<50)? Wt[d*FT+f] : 0.f; return; }
  id -= 19968;
  if (id < 19968){ int f=id/52, d=id%52; ws[O_WIT+id] = (f<383 && d<50)? Wi[d*FI+f] : 0.f; return; }
  id -= 19968;
  if (id < 10400){ int m=id/52, o=id%52; int t=m/50, d=m%50;
                   ws[O_WIP+id] = (o<50)? Wip[o*200+t*50+d]*g[d] : 0.f; return; }
  id -= 10400;
  if (id < 62400){ int m=id/52, o=id%52; int i=m/50, d=m%50;
                   ws[O_WTP+id] = (o<50)? Wtp[o*1200+i*50+d]*g[d] : 0.f; return; }
  id -= 62400;
  if (id < 50000){ int e=id/100, k=id%100; ws[O_W1T+id] = W1[k*1000+e]; return; }
  id -= 50000;
  if (id < 50000){ int k=id/500, e=id%500; ws[O_W3T+id] = W3[e*100+k]; return; }
  id -= 50000;
  if (id < 208){ int t=id/52, o=id%52; float s=0;
                 if (o<50) for(int d=0;d<50;d++) s += Wip[o*200+t*50+d]*g[d];
                 ws[O_SIP+id]=s; return; }
  id -= 208;
  if (id < 1248){ int i=id/52, o=id%52; float s=0;
                  if (o<50) for(int d=0;d<50;d++) s += Wtp[o*1200+i*50+d]*g[d];
                  ws[O_STP+id]=s; return; }
  id -= 1248;
  if (id < 52){ int o=id; float s=0;
                if (o<50){ for(int j=0;j<200;j++) s += lb[j%50]*Wip[o*200+j]; s=2.f*s+bip[o]; }
                ws[O_CBI+o]=s; return; }
  id -= 52;
  if (id < 52){ int o=id; float s=0;
                if (o<50){ for(int j=0;j<1200;j++) s += lb[j%50]*Wtp[o*1200+j]; s=2.f*s+btp[o]; }
                ws[O_CBT+o]=s; return; }
  id -= 52;
  if (id < 51200){ int k=id/512, e=id%512;
                   ws[O_W3P+id] = (e<500)? W3[e*100+k] : 0.f; return; }
}

// ---------------- per-batch relation gates ----------------
__global__ void k_rel(const int* ps, const float* rele, const float* Wr1, const float* br1,
                      const float* Wr2, const float* br2, const float* W1, float* ws){
  __shared__ float relL[EE];
  int b = blockIdx.x;
  int r = ps[b*3+1];
  for (int e=threadIdx.x; e<EE; e+=256) relL[e] = rele[(size_t)r*EE+e];
  __syncthreads();
  for (int j=threadIdx.x; j<292; j+=256){
    if (j<96){
      float a=br1[j]; const float* w=&Wr1[j*EE];
      for(int e=0;e<EE;e++) a+=relL[e]*w[e];
      ws[O_RGI+b*96+j]=sigm(a);
    } else if (j<192){
      int jj=j-96; float a=br2[jj]; const float* w=&Wr2[jj*EE];
      for(int e=0;e<EE;e++) a+=relL[e]*w[e];
      ws[O_RGT+b*96+jj]=sigm(a);
    } else {
      int k=j-192; float a=0; const float* w=&W1[k*1000+500];
      for(int e=0;e<EE;e++) a+=relL[e]*w[e];
      ws[O_RB+b*100+k]=a;
    }
  }
}

// ---------------- A[n,k] = ent @ W1[:, :E]^T ----------------
__global__ void k_A(const float* ent, float* ws){
  __shared__ float entL[8*EE];
  int n0 = blockIdx.x*8;
  for (int idx=threadIdx.x; idx<8*EE; idx+=256) entL[idx] = ent[(size_t)n0*EE + idx];
  __syncthreads();
  const float* W1T = &ws[O_W1T];
  for (int idx=threadIdx.x; idx<800; idx+=256){
    int rr=idx/100, k=idx%100; float a=0;
    const float* el=&entL[rr*EE];
    for (int e=0;e<EE;e++) a += el[e]*W1T[e*100+k];
    ws[O_A + (size_t)(n0+rr)*100 + k] = a;
  }
}

// ---------------- pos_t vectors (also transposed copy) ----------------
__global__ void k_pos(const int* ps, const float* ent, const float* b1, const float* b3, float* ws){
  __shared__ float hL[KH];
  __shared__ float red[4];
  int b=blockIdx.x; int n=ps[b*3+2]; int tid=threadIdx.x;
  if (tid<KH) hL[tid] = leaky(ws[O_A+(size_t)n*100+tid] + ws[O_RB+b*100+tid] + b1[tid]);
  __syncthreads();
  const float* w3t=&ws[O_W3T];
  float sq=0;
  for (int e=tid; e<EE; e+=256){
    float a=b3[e];
    for (int k=0;k<KH;k++) a += hL[k]*w3t[k*500+e];
    float gg=sigm(a); float ta=ent[(size_t)n*EE+e]*gg;
    ws[O_PT+b*500+e]=ta;
    ws[O_PTT+(size_t)e*32+b]=ta;
    sq+=ta*ta;
  }
  for (int off=1; off<64; off<<=1) sq += __shfl_xor(sq, off);
  if ((tid&63)==0) red[tid>>6]=sq;
  __syncthreads();
  if (tid==0) ws[O_PTN+b] = sqrtf(red[0]+red[1]+red[2]+red[3]);
}

// ---------------- embedding GEMM: one row/lane, W chunks in LDS ----------------
__global__ __launch_bounds__(256) void k_emb(const float* X, const float* Wp, const float* bias,
                                             float* emb, int R, int F, int rowsPerN, int rowOff,
                                             int xstride){
  __shared__ __align__(16) float Wl[128*52];
  int row = blockIdx.x*256 + threadIdx.x;
  bool act = row < R;
  float4 acc[13];
  #pragma unroll
  for (int c=0;c<13;c++) acc[c]=make_float4(0,0,0,0);
  const float* xr = X + (size_t)(act?row:0)*xstride;
  for (int f0=0; f0<F; f0+=128){
    int nf = min(128, F-f0);
    __syncthreads();
    for (int j=threadIdx.x; j<nf*52; j+=256) Wl[j] = Wp[(size_t)f0*52 + j];
    __syncthreads();
    if (act){
      for (int f=0; f<nf; ++f){
        float x = xr[f0+f];
        const float4* wr = (const float4*)&Wl[f*52];
        #pragma unroll
        for (int c=0;c<13;++c){
          float4 w=wr[c];
          acc[c].x+=x*w.x; acc[c].y+=x*w.y; acc[c].z+=x*w.z; acc[c].w+=x*w.w;
        }
      }
    }
  }
  if (act){
    int n = row / rowsPerN, rr = row % rowsPerN;
    float* dst = emb + (size_t)n*1456 + (size_t)(rowOff+rr)*52;
    #pragma unroll
    for (int c=0;c<13;++c){
      float4 v=acc[c]; int o=c*4;
      v.x=leaky(v.x+bias[o]); v.y=leaky(v.y+bias[o+1]);
      if (c<12){ v.z=leaky(v.z+bias[o+2]); v.w=leaky(v.w+bias[o+3]); }
      else { v.z=0.f; v.w=0.f; }
      *(float4*)&dst[o]=v;
    }
  }
}

// ---------------- fused per-n kernel (mode 0: all n; mode 1: pos rows per b) ----------------
__global__ __launch_bounds__(256) void k_main(const int* ps, float* ws, float* out, int mode){
  __shared__ __align__(16) float teie[1456];
  __shared__ __align__(16) float Pm[120*52];
  __shared__ __align__(16) float Um[120*32];
  __shared__ __align__(16) float Gi[576];
  __shared__ __align__(16) float crs[96];
  __shared__ __align__(16) float aimg[96], atxt[96];
  __shared__ __align__(16) float part1[96], part2[96];
  __shared__ __align__(16) float aU[120];
  __shared__ __align__(16) float PattC[52], QattC[52];
  __shared__ float Gts[16], mimg[24], mtxt[4];
  __shared__ float muA1[4], muA2[24];
  __shared__ float accD1[32], accN1[32], accD2[32], accN2[32];

  int tid = threadIdx.x;
  int bstar = blockIdx.x;
  int n = mode ? ps[bstar*3+2] : blockIdx.x;

  // P0: stage emb row block, zero accumulators
  const float* embn = &ws[O_EMB + (size_t)n*1456];
  for (int j=tid; j<364; j+=256) *(float4*)&teie[j*4] = *(const float4*)&embn[j*4];
  if (tid<32){ accD1[tid]=0.f; accN1[tid]=0.f; accD2[tid]=0.f; accN2[tid]=0.f; }
  __syncthreads();

  // P1: Gram matrices, cross, means
  for (int it=tid; it<716; it+=256){
    if (it<576){
      int i=it/24, j=it%24; float s=0;
      const float* a=&teie[(4+i)*52]; const float* b=&teie[(4+j)*52];
      for(int d=0;d<50;d++) s+=a[d]*b[d];
      Gi[it]=s;
    } else if (it<672){
      int c=it-576; int i=c>>2, t=c&3; float s=0;
      const float* a=&teie[(4+i)*52]; const float* b=&teie[t*52];
      for(int d=0;d<50;d++) s+=a[d]*b[d];
      crs[c]=s;
    } else if (it<688){
      int c=it-672; int t=c>>2, u=c&3; float s=0;
      const float* a=&teie[t*52]; const float* b=&teie[u*52];
      for(int d=0;d<50;d++) s+=a[d]*b[d];
      Gts[c]=s;
    } else if (it<712){
      int i=it-688; float s=0; const float* a=&teie[(4+i)*52];
      for(int d=0;d<50;d++) s+=a[d];
      mimg[i]=s*0.02f;
    } else {
      int t=it-712; float s=0; const float* a=&teie[t*52];
      for(int d=0;d<50;d++) s+=a[d];
      mtxt[t]=s*0.02f;
    }
  }
  __syncthreads();

  // P2: attention softmaxes + means
  if (tid<4){
    int t=tid;
    float mx=-1e30f; for(int i=0;i<24;i++) mx=fmaxf(mx,crs[i*4+t]);
    float ex[24]; float s=0;
    for(int i=0;i<24;i++){ ex[i]=__expf(crs[i*4+t]-mx); s+=ex[i]; }
    float inv=1.f/s; float mu=0;
    for(int i=0;i<24;i++){ float a=ex[i]*inv; aimg[i*4+t]=a; mu+=a*mimg[i]; }
    muA1[t]=mu;
  } else if (tid>=64 && tid<88){
    int i=tid-64;
    float mx=-1e30f; for(int t=0;t<4;t++) mx=fmaxf(mx,crs[i*4+t]);
    float ex[4]; float s=0;
    for(int t=0;t<4;t++){ ex[t]=__expf(crs[i*4+t]-mx); s+=ex[t]; }
    float inv=1.f/s; float mu=0;
    for(int t=0;t<4;t++){ float a=ex[t]*inv; atxt[i*4+t]=a; mu+=a*mtxt[t]; }
    muA2[i]=mu;
  }
  __syncthreads();

  // P3: build P = ipb rows [z=t*24+i][52] + Sip rows; att quadratic partials
  const float* WIPg=&ws[O_WIP];
  for (int it=tid; it<1248; it+=256){
    int z=it/13, q=it%13; int t=z/24, i=z%24;
    const float* wb=&WIPg[(size_t)(t*50)*52 + q*4];
    const float* ieb=&teie[(4+i)*52];
    float4 a=make_float4(0,0,0,0);
    for (int d=0; d<50; ++d){
      float e=ieb[d];
      float4 w=*(const float4*)&wb[(size_t)d*52];
      a.x+=e*w.x; a.y+=e*w.y; a.z+=e*w.z; a.w+=e*w.w;
    }
    *(float4*)&Pm[z*52+q*4]=a;
  }
  for (int j=tid; j<208; j+=256) Pm[96*52+j]=ws[O_SIP+j];
  if (tid<96){
    int i=tid>>2, t=tid&3;
    float s=0; for(int j=0;j<24;j++) s+=Gi[i*24+j]*aimg[j*4+t];
    part1[tid]=aimg[tid]*s;
  } else if (tid<192){
    int c=tid-96; int t=c&3;
    float s=0; for(int u=0;u<4;u++) s+=Gts[t*4+u]*atxt[(c&~3)+u];
    part2[c]=atxt[c]*s;
  }
  __syncthreads();

  // P4: img LN stats -> U ; att aU
  if (tid<128){
    int b=tid&31, t=tid>>5;
    float w1r[24];
    for(int i=0;i<24;i++) w1r[i]=ws[O_RGI+b*96+i*4+t]*crs[i*4+t];
    float mu=0; for(int i=0;i<24;i++) mu+=w1r[i]*mimg[i];
    float q=0;
    for(int i=0;i<24;i++){ float s=0; for(int j=0;j<24;j++) s+=Gi[i*24+j]*w1r[j]; q+=w1r[i]*s; }
    float inv=rsqrtf(q*0.02f-mu*mu+1e-5f);
    for(int i=0;i<24;i++) Um[(t*24+i)*32+b]=inv*w1r[i];
    Um[(96+t)*32+b]=-inv*mu;
  } else if (tid<228){
    int z=tid-128;
    int t=(z<96)? (z/24) : (z-96);
    float q=0; for(int i=0;i<24;i++) q+=part1[i*4+t];
    float inv=rsqrtf(q*0.02f-muA1[t]*muA1[t]+1e-5f);
    aU[z]=(z<96)? inv*aimg[(z%24)*4+t] : -inv*muA1[t];
  }
  __syncthreads();

  // P4b: PattC
  if (tid<52){
    float s=ws[O_CBI+tid];
    for(int z=0;z<100;z++) s+=aU[z]*Pm[z*52+tid];
    PattC[tid]=s;
  }
  __syncthreads();

  // P5: img GEMM + fused cos-sim partials
  {
    int b=tid&31, q0=tid>>5;
    bool h2=(q0+8)<13;
    float4 a0=make_float4(0,0,0,0), a1=make_float4(0,0,0,0);
    #pragma unroll 4
    for (int z=0; z<100; ++z){
      float u=Um[z*32+b];
      float4 p0=*(const float4*)&Pm[z*52+q0*4];
      a0.x+=u*p0.x; a0.y+=u*p0.y; a0.z+=u*p0.z; a0.w+=u*p0.w;
      if (h2){
        float4 p1=*(const float4*)&Pm[z*52+(q0+8)*4];
        a1.x+=u*p1.x; a1.y+=u*p1.y; a1.z+=u*p1.z; a1.w+=u*p1.w;
      }
    }
    float4 c0=*(const float4*)&PattC[q0*4];
    a0.x+=c0.x; a0.y+=c0.y; a0.z+=c0.z; a0.w+=c0.w;
    if (h2){ float4 c1=*(const float4*)&PattC[(q0+8)*4]; a1.x+=c1.x; a1.y+=c1.y; a1.z+=c1.z; a1.w+=c1.w; }
    float ni=a0.x*a0.x+a0.y*a0.y+a0.z*a0.z+a0.w*a0.w;
    if (h2) ni+=a1.x*a1.x+a1.y*a1.y+a1.z*a1.z+a1.w*a1.w;
    if (!mode){
      const float* pv=&ws[O_PIM+b*52];
      float4 p0=*(const float4*)&pv[q0*4];
      float di=a0.x*p0.x+a0.y*p0.y+a0.z*p0.z+a0.w*p0.w;
      if (h2){
        float4 p1=*(const float4*)&pv[(q0+8)*4];
        di+=a1.x*p1.x+a1.y*p1.y+a1.z*p1.z+a1.w*p1.w;
      }
      atomicAdd(&accD1[b],di); atomicAdd(&accN1[b],ni);
    } else {
      atomicAdd(&accN1[b],ni);
      if (b==bstar){
        *(float4*)&ws[O_PIM+b*52+q0*4]=a0;
        if (h2) *(float4*)&ws[O_PIM+b*52+(q0+8)*4]=a1;
      }
    }
  }
  __syncthreads();

  // P6: write img sims / norms; build P = tpb + Stp rows
  if (!mode){
    if (tid<32)
      out[(size_t)BN + (size_t)tid*NN + n] = accD1[tid]/(sqrtf(accN1[tid])*ws[O_PIMN+tid]+1e-10f);
  } else {
    if (tid==0) ws[O_PIMN+bstar]=sqrtf(accN1[bstar]);
  }
  {
    const float* WTPg=&ws[O_WTP];
    for (int it=tid; it<1248; it+=256){
      int z=it/13, q=it%13; int t=z/24, i=z%24;
      const float* wb=&WTPg[(size_t)(i*50)*52 + q*4];
      const float* teb=&teie[t*52];
      float4 a=make_float4(0,0,0,0);
      for (int d=0; d<50; ++d){
        float e=teb[d];
        float4 w=*(const float4*)&wb[(size_t)d*52];
        a.x+=e*w.x; a.y+=e*w.y; a.z+=e*w.z; a.w+=e*w.w;
      }
      *(float4*)&Pm[z*52+q*4]=a;
    }
    for (int j=tid; j<1248; j+=256) Pm[96*52+j]=ws[O_STP+j];
  }
  __syncthreads();

  // P7: text LN stats -> U ; att aU2
  for (int it=tid; it<888; it+=256){
    if (it<768){
      int b=it&31, i=it>>5;
      float w2r[4];
      for(int t=0;t<4;t++) w2r[t]=ws[O_RGT+b*96+i*4+t]*crs[i*4+t];
      float mu=0; for(int t=0;t<4;t++) mu+=w2r[t]*mtxt[t];
      float q=0;
      for(int t=0;t<4;t++){ float s=0; for(int u=0;u<4;u++) s+=Gts[t*4+u]*w2r[u]; q+=w2r[t]*s; }
      float inv=rsqrtf(q*0.02f-mu*mu+1e-5f);
      for(int t=0;t<4;t++) Um[(t*24+i)*32+b]=inv*w2r[t];
      Um[(96+i)*32+b]=-inv*mu;
    } else {
      int z=it-768;
      int i=(z<96)? (z%24) : (z-96);
      float q=0; for(int t=0;t<4;t++) q+=part2[i*4+t];
      float inv=rsqrtf(q*0.02f-muA2[i]*muA2[i]+1e-5f);
      aU[z]=(z<96)? inv*atxt[(z%24)*4+(z/24)] : -inv*muA2[i];
    }
  }
  __syncthreads();

  // P7b: QattC
  if (tid<52){
    float s=ws[O_CBT+tid];
    for(int z=0;z<120;z++) s+=aU[z]*Pm[z*52+tid];
    QattC[tid]=s;
  }
  __syncthreads();

  // P8: text GEMM + fused cos-sim partials
  {
    int b=tid&31, q0=tid>>5;
    bool h2=(q0+8)<13;
    float4 a0=make_float4(0,0,0,0), a1=make_float4(0,0,0,0);
    #pragma unroll 4
    for (int z=0; z<120; ++z){
      float u=Um[z*32+b];
      float4 p0=*(const float4*)&Pm[z*52+q0*4];
      a0.x+=u*p0.x; a0.y+=u*p0.y; a0.z+=u*p0.z; a0.w+=u*p0.w;
      if (h2){
        float4 p1=*(const float4*)&Pm[z*52+(q0+8)*4];
        a1.x+=u*p1.x; a1.y+=u*p1.y; a1.z+=u*p1.z; a1.w+=u*p1.w;
      }
    }
    float4 c0=*(const float4*)&QattC[q0*4];
    a0.x+=c0.x; a0.y+=c0.y; a0.z+=c0.z; a0.w+=c0.w;
    if (h2){ float4 c1=*(const float4*)&QattC[(q0+8)*4]; a1.x+=c1.x; a1.y+=c1.y; a1.z+=c1.z; a1.w+=c1.w; }
    float ni=a0.x*a0.x+a0.y*a0.y+a0.z*a0.z+a0.w*a0.w;
    if (h2) ni+=a1.x*a1.x+a1.y*a1.y+a1.z*a1.z+a1.w*a1.w;
    if (!mode){
      const float* pv=&ws[O_PTX+b*52];
      float4 p0=*(const float4*)&pv[q0*4];
      float di=a0.x*p0.x+a0.y*p0.y+a0.z*p0.z+a0.w*p0.w;
      if (h2){
        float4 p1=*(const float4*)&pv[(q0+8)*4];
        di+=a1.x*p1.x+a1.y*p1.y+a1.z*p1.z+a1.w*p1.w;
      }
      atomicAdd(&accD2[b],di); atomicAdd(&accN2[b],ni);
    } else {
      atomicAdd(&accN2[b],ni);
      if (b==bstar){
        *(float4*)&ws[O_PTX+b*52+q0*4]=a0;
        if (h2) *(float4*)&ws[O_PTX+b*52+(q0+8)*4]=a1;
      }
    }
  }
  __syncthreads();

  // P9: write text sims / norms
  if (!mode){
    if (tid<32)
      out[2*(size_t)BN + (size_t)tid*NN + n] = accD2[tid]/(sqrtf(accN2[tid])*ws[O_PTXN+tid]+1e-10f);
  } else {
    if (tid==0) ws[O_PTXN+bstar]=sqrtf(accN2[bstar]);
  }
}

// ---------------- fused gate GEMM + t-path cos-sim: 8e x 8b register tile ----------------
// eslot=tid&63 (64 x 8e = 512 e, padded), wave=tid>>6 owns 8 b's.
// w3c reads: lane-distinct 2x b128 (intrinsic 8-cyc 1KB pattern, conflict-free-equiv).
// hallT reads: wave-uniform address -> broadcast (free).
__global__ __launch_bounds__(256) void k_gate(const float* ent, const float* b1, const float* b3,
                                              float* ws, float* out){
  __shared__ __align__(16) float w3c[25*512];   // 51.2 KB, k-chunk of W3P
  __shared__ __align__(16) float hallT[KH*32];  // [k][b] 12.8 KB
  __shared__ float entL[512], b3L[512];
  __shared__ float numL[BB], sqL[BB];
  int n=blockIdx.x, tid=threadIdx.x;

  for (int e=tid; e<EE; e+=256){ entL[e]=ent[(size_t)n*EE+e]; b3L[e]=b3[e]; }
  if (tid<12){ entL[500+tid]=0.f; b3L[500+tid]=0.f; }
  for (int idx=tid; idx<KH*32; idx+=256){
    int k=idx>>5, b=idx&31;
    hallT[idx] = leaky(ws[O_A+(size_t)n*KH+k] + ws[O_RB+b*KH+k] + b1[k]);
  }

  int eslot = tid&63, wv = tid>>6;
  int e0 = eslot*8, b0 = wv*8;
  float acc[8][8];   // [b][e]
  #pragma unroll
  for (int i=0;i<8;i++)
    #pragma unroll
    for (int j=0;j<8;j++) acc[i][j]=0.f;

  const float* W3P=&ws[O_W3P];
  for (int kc=0;kc<4;kc++){
    __syncthreads();
    for (int idx=tid; idx<3200; idx+=256)
      *(float4*)&w3c[idx*4] = *(const float4*)&W3P[(size_t)kc*12800 + (size_t)idx*4];
    __syncthreads();
    const float* hb=&hallT[kc*25*32 + b0];
    #pragma unroll 1
    for (int k=0;k<25;k++){
      float4 w0=*(const float4*)&w3c[k*512+e0];
      float4 w1=*(const float4*)&w3c[k*512+e0+4];
      float4 h0=*(const float4*)&hb[k*32];
      float4 h1=*(const float4*)&hb[k*32+4];
      float wr[8]={w0.x,w0.y,w0.z,w0.w,w1.x,w1.y,w1.z,w1.w};
      float hr[8]={h0.x,h0.y,h0.z,h0.w,h1.x,h1.y,h1.z,h1.w};
      #pragma unroll
      for (int i=0;i<8;i++)
        #pragma unroll
        for (int j=0;j<8;j++)
          acc[i][j] += hr[i]*wr[j];
    }
  }

  // epilogue: gate, t_att, cos-sim partials over this thread's 8 e's
  float pn[8], ps[8];
  #pragma unroll
  for (int i=0;i<8;i++){ pn[i]=0.f; ps[i]=0.f; }
  const float* PTT=&ws[O_PTT];
  #pragma unroll 1
  for (int j=0;j<8;j++){
    int e=e0+j;
    float be=b3L[e], ev=entL[e];          // pad rows: ev=0 -> t=0
    float4 pA=*(const float4*)&PTT[(size_t)e*32+b0];
    float4 pB=*(const float4*)&PTT[(size_t)e*32+b0+4];
    float pv[8]={pA.x,pA.y,pA.z,pA.w,pB.x,pB.y,pB.z,pB.w};
    #pragma unroll
    for (int i=0;i<8;i++){
      float t = ev*sigm(acc[i][j]+be);
      pn[i]+=t*pv[i]; ps[i]+=t*t;
    }
  }
  for (int off=1; off<64; off<<=1){
    #pragma unroll
    for (int i=0;i<8;i++){ pn[i]+=__shfl_xor(pn[i],off); ps[i]+=__shfl_xor(ps[i],off); }
  }
  if (eslot==0){
    #pragma unroll
    for (int i=0;i<8;i++){ numL[b0+i]=pn[i]; sqL[b0+i]=ps[i]; }
  }
  __syncthreads();
  if (tid<BB)
    out[3*(size_t)BN + (size_t)tid*NN + n] = numL[tid]/(sqrtf(sqL[tid])*ws[O_PTN+tid]+1e-10f);
}

// ---------------- softmax pass 1 ----------------
__global__ void k_smax1(const float* out, float* ws){
  __shared__ float red[4];
  __shared__ float Msh;
  int a=blockIdx.x>>5, b=blockIdx.x&31, tid=threadIdx.x;
  const float* arr=&out[(size_t)(1+a)*BN + (size_t)b*NN];
  float mx=-1e30f;
  for (int i=tid;i<NN;i+=256) mx=fmaxf(mx,arr[i]);
  for (int off=1;off<64;off<<=1) mx=fmaxf(mx,__shfl_xor(mx,off));
  if ((tid&63)==0) red[tid>>6]=mx;
  __syncthreads();
  if (tid==0) Msh=fmaxf(fmaxf(red[0],red[1]),fmaxf(red[2],red[3]));
  __syncthreads();
  float M2=2.f*Msh;
  float s=0;
  for (int i=tid;i<NN;i+=256) s+=__expf(2.f*arr[i]-M2);
  for (int off=1;off<64;off<<=1) s+=__shfl_xor(s,off);
  if ((tid&63)==0) red[tid>>6]=s;
  __syncthreads();
  if (tid==0){ ws[O_MR+a*32+b]=M2; ws[O_SR+a*32+b]=red[0]+red[1]+red[2]+red[3]; }
}

// ---------------- softmax pass 2 ----------------
__global__ void k_smax2(float* out, const float* ws){
  int t=blockIdx.x*256+threadIdx.x;
  if (t>=BN) return;
  int b=t/NN;
  float r=0;
  for (int a=0;a<3;a++)
    r += __expf(2.f*out[(size_t)(1+a)*BN+t]-ws[O_MR+a*32+b])/ws[O_SR+a*32+b];
  out[t]=r;
}

extern "C" void kernel_launch(void* const* d_in, const int* in_sizes, int n_in,
                              void* d_out, int out_size, void* d_ws, size_t ws_size,
                              hipStream_t stream){
  (void)in_sizes; (void)n_in; (void)out_size; (void)ws_size;
  const int*   ps  =(const int*)  d_in[0];
  const float* etg =(const float*)d_in[1];
  const float* eig =(const float*)d_in[2];
  const float* ent =(const float*)d_in[3];
  const float* rele=(const float*)d_in[4];
  const float* Wt  =(const float*)d_in[5];
  const float* btx =(const float*)d_in[6];
  const float* Wi  =(const float*)d_in[7];
  const float* bim =(const float*)d_in[8];
  const float* Wtp =(const float*)d_in[9];
  const float* btp =(const float*)d_in[10];
  const float* Wip =(const float*)d_in[11];
  const float* bip =(const float*)d_in[12];
  const float* Wr1 =(const float*)d_in[13];
  const float* br1 =(const float*)d_in[14];
  const float* Wr2 =(const float*)d_in[15];
  const float* br2 =(const float*)d_in[16];
  const float* W1  =(const float*)d_in[17];
  const float* b1  =(const float*)d_in[18];
  const float* W3  =(const float*)d_in[19];
  const float* b3  =(const float*)d_in[20];
  const float* lng =(const float*)d_in[21];
  const float* lnb =(const float*)d_in[22];
  float* ws =(float*)d_ws;
  float* out=(float*)d_out;

  k_prep <<<1038,256,0,stream>>>(Wt,Wi,Wip,Wtp,W1,W3,lng,lnb,bip,btp,ws);
  k_rel  <<<32, 256,0,stream>>>(ps,rele,Wr1,br1,Wr2,br2,W1,ws);
  k_A    <<<625,256,0,stream>>>(ent,ws);
  k_pos  <<<32, 256,0,stream>>>(ps,ent,b1,b3,ws);
  k_emb  <<<79, 256,0,stream>>>(etg,&ws[O_WTT],btx,&ws[O_EMB],20000,FT,4,0,FT);
  k_emb  <<<469,256,0,stream>>>(eig,&ws[O_WIT],bim,&ws[O_EMB],120000,FI,24,4,FI);
  k_main <<<32,  256,0,stream>>>(ps,ws,out,1);
  k_main <<<5000,256,0,stream>>>(ps,ws,out,0);
  k_gate <<<5000,256,0,stream>>>(ent,b1,b3,ws,out);
  k_smax1<<<96, 256,0,stream>>>(out,ws);
  k_smax2<<<625,256,0,stream>>>(out,ws);
}